// Round 1
// baseline (236.684 us; speedup 1.0000x reference)
//
#include <hip/hip_runtime.h>

#define D_DIM 256
#define STEP (6.0f / 255.0f)
#define CAP 16          // max points per pixel bin (Poisson lambda~1.1 -> P(>16)~1e-14)
#define LOG2E 1.4426950408889634f

// ---- Pass 1: normalize + direct-slot fill. ONE THREAD PER POINT. ----
// The per-point constant scale of log_prob cancels in L2 normalization, so
// probs ∝ exp(a*xt^2), a = -0.5*(STEP/conf)^2. The squared-norm over the
// 256-window splits into two one-sided Gaussian sums F(dep) + F(254-dep),
// F(n) = sum_{j=0}^{n} exp(-s2*j^2), s2 = -2a, evaluated in closed form via
// Euler-Maclaurin: F(n) = sqrt(pi)/(2s)*erf(s*n) + (1+E)/2 - s2*n*E/6,
// E = exp(-s2*n^2). Truncation error < 1e-5 relative for s2 <= 0.0023.
// Record: {depth(bits), A2 = a*log2e, inv_nrm, Q = 2^(2*A2)}.
__global__ __launch_bounds__(256) void normfill_kernel(
    const int2* __restrict__ pts_pos, const int* __restrict__ pts_depth,
    const float* __restrict__ pts_conf, const int* __restrict__ feat_w,
    int* __restrict__ counts, float4* __restrict__ bins, int N)
{
    const int p = blockIdx.x * 256 + threadIdx.x;
    if (p >= N) return;

    const int dep = pts_depth[p];
    const float ic = 1.0f / pts_conf[p];
    const float s  = STEP * ic;
    const float s2 = s * s;                 // = -2a
    const float a  = -0.5f * s2;

    const float c0 = 0.8862269254527580f / s;   // sqrt(pi)/2 / s
    const float n1 = (float)dep;
    const float n2 = (float)(254 - dep);
    const float E1 = __expf(-s2 * n1 * n1);
    const float E2 = __expf(-s2 * n2 * n2);
    const float F1 = c0 * erff(s * n1) + 0.5f * (1.f + E1) - s2 * n1 * E1 * (1.f / 6.f);
    const float F2 = c0 * erff(s * n2) + 0.5f * (1.f + E2) - s2 * n2 * E2 * (1.f / 6.f);
    const float ss = F1 + F2;

    const int W = *feat_w;
    const int2 uv = pts_pos[p];
    const int lin = uv.y * W + uv.x;
    const int slot = atomicAdd(&counts[lin], 1);
    if (slot < CAP) {
        const float A2 = a * LOG2E;
        float4 rec;
        rec.x = __int_as_float(dep);
        rec.y = A2;
        rec.z = rsqrtf(ss);
        rec.w = exp2f(2.0f * A2);           // geometric ratio-of-ratios Q
        bins[(size_t)lin * CAP + slot] = rec;
    }
}

// ---- Pass 2: gather + write in [D, HW] layout. ----
// Block 256 = 4 waves. lane = pixel within a 64-pixel tile; wave selects a
// 64-depth slab, so ONE block covers all 256 depths for its 64 pixels
// (v2: was 32 depths + grid.y=2 → each pixel's records were re-read by 8
// slabs; now 4 — halves bin re-reads and per-record exp2 setup).
// Inner loop uses the Gaussian recurrence g(t+1) = g(t)*r, r *= Q — no
// transcendentals; one predicated skip at the t=0->1 kink (xt repeats).
// acc[64] in registers (~96 VGPR, ~4-5 waves/SIMD — enough to stream
// stores); coalesced 256 B output rows; no LDS, no atomics.
__global__ __launch_bounds__(256) void gather_kernel(
    const int* __restrict__ counts, const float4* __restrict__ bins,
    float* __restrict__ out, int HW)
{
    const int wave = threadIdx.x >> 6;
    const int lane = threadIdx.x & 63;
    const int pix = blockIdx.x * 64 + lane;
    const int db  = wave * 64;              // first depth of this slab

    float acc[64];
#pragma unroll
    for (int k = 0; k < 64; ++k) acc[k] = 0.f;

    if (pix < HW) {
        int cnt = counts[pix];
        cnt = cnt < CAP ? cnt : CAP;
        const float4* __restrict__ rec = bins + (size_t)pix * CAP;
        for (int j = 0; j < cnt; ++j) {
            const float4 r4 = rec[j];
            const int dep   = __float_as_int(r4.x);
            const float A2  = r4.y;
            const float inv = r4.z;
            const float Q   = r4.w;

            const int t0  = db - dep;
            const int xt0 = t0 - (t0 > 0);
            const float fx = (float)xt0;
            float g = exp2f(A2 * fx * fx) * inv;      // inv folded once per rec
            float r = exp2f(A2 * (2.0f * fx + 1.0f));
            const int skipK = -t0;             // at k==skipK, t goes 0->1: xt repeats
#pragma unroll
            for (int k = 0; k < 64; ++k) {
                acc[k] += g;
                const bool adv = (k != skipK);
                g = adv ? g * r : g;
                r = adv ? r * Q : r;
            }
        }

        float* o = out + (size_t)db * HW + pix;
#pragma unroll
        for (int k = 0; k < 64; ++k) {
            __builtin_nontemporal_store(acc[k], o);
            o += HW;
        }
    }
}

// ---------------- Fallback: direct scattered atomics ----------------
__global__ __launch_bounds__(256) void scatter_direct_kernel(
    const int* __restrict__ pts_pos, const int* __restrict__ pts_depth,
    const float* __restrict__ pts_conf, const int* __restrict__ feat_w,
    float* __restrict__ out, int HW, int N)
{
    const int wave = threadIdx.x >> 6;
    const int lane = threadIdx.x & 63;
    const int p = blockIdx.x * 4 + wave;
    if (p >= N) return;

    const int W = *feat_w;
    const int lin = pts_pos[2 * p + 1] * W + pts_pos[2 * p];
    const int dep = pts_depth[p];
    const float ic = 1.0f / pts_conf[p];

    float pr[4];
    float ss = 0.f;
#pragma unroll
    for (int k = 0; k < 4; ++k) {
        const int d = lane + 64 * k;
        const int t = d - dep;
        const float x = (float)(t > 0 ? t - 1 : t) * STEP;
        const float z = x * ic;
        const float e = __expf(-0.5f * z * z);
        pr[k] = e;
        ss += e * e;
    }
#pragma unroll
    for (int off = 32; off; off >>= 1) ss += __shfl_xor(ss, off, 64);
    const float inv = rsqrtf(ss);
#pragma unroll
    for (int k = 0; k < 4; ++k) {
        const int d = lane + 64 * k;
        atomicAdd(out + (size_t)d * HW + lin, pr[k] * inv);
    }
}

extern "C" void kernel_launch(void* const* d_in, const int* in_sizes, int n_in,
                              void* d_out, int out_size, void* d_ws, size_t ws_size,
                              hipStream_t stream) {
    const int*   pts_pos   = (const int*)d_in[0];
    const int*   pts_depth = (const int*)d_in[1];
    const float* pts_conf  = (const float*)d_in[2];
    const int*   feat_w    = (const int*)d_in[4];

    const int N  = in_sizes[0] / 2;
    const int HW = out_size / D_DIM;
    float* out = (float*)d_out;

    // ws layout: [bins: HW*CAP float4 | counts: HW int]
    float4* bins  = (float4*)d_ws;
    int* counts   = (int*)(bins + (size_t)HW * CAP);
    const size_t ws_need = (size_t)HW * CAP * sizeof(float4) + (size_t)HW * sizeof(int);

    if (ws_size >= ws_need) {
        (void)hipMemsetAsync(counts, 0, (size_t)HW * sizeof(int), stream);
        normfill_kernel<<<(N + 255) / 256, 256, 0, stream>>>(
            (const int2*)pts_pos, pts_depth, pts_conf, feat_w, counts, bins, N);
        gather_kernel<<<(HW + 63) / 64, 256, 0, stream>>>(counts, bins, out, HW);
    } else {
        (void)hipMemsetAsync(d_out, 0, (size_t)out_size * sizeof(float), stream);
        scatter_direct_kernel<<<(N + 3) / 4, 256, 0, stream>>>(
            pts_pos, pts_depth, pts_conf, feat_w, out, HW, N);
    }
}

// Round 2
// 229.668 us; speedup vs baseline: 1.0306x; 1.0306x over previous
//
#include <hip/hip_runtime.h>

#define D_DIM 256
#define STEP (6.0f / 255.0f)
#define CAP 16          // max points per pixel bin (Poisson lambda~1.1 -> P(>16)~1e-14)
#define LOG2E 1.4426950408889634f

// ---- Pass 1: normalize + direct-slot fill. ONE THREAD PER POINT. ----
// The per-point constant scale of log_prob cancels in L2 normalization, so
// probs ∝ exp(a*xt^2), a = -0.5*(STEP/conf)^2. The squared-norm over the
// 256-window splits into two one-sided Gaussian sums F(dep) + F(254-dep),
// F(n) = sum_{j=0}^{n} exp(-s2*j^2), s2 = -2a, evaluated in closed form via
// Euler-Maclaurin: F(n) = sqrt(pi)/(2s)*erf(s*n) + (1+E)/2 - s2*n*E/6,
// E = exp(-s2*n^2). Truncation error < 1e-5 relative for s2 <= 0.0023.
// Record: {depth(bits), A2 = a*log2e, inv_nrm, Q = 2^(2*A2)}.
__global__ __launch_bounds__(256) void normfill_kernel(
    const int2* __restrict__ pts_pos, const int* __restrict__ pts_depth,
    const float* __restrict__ pts_conf, const int* __restrict__ feat_w,
    int* __restrict__ counts, float4* __restrict__ bins, int N)
{
    const int p = blockIdx.x * 256 + threadIdx.x;
    if (p >= N) return;

    const int dep = pts_depth[p];
    const float ic = 1.0f / pts_conf[p];
    const float s  = STEP * ic;
    const float s2 = s * s;                 // = -2a
    const float a  = -0.5f * s2;

    const float c0 = 0.8862269254527580f / s;   // sqrt(pi)/2 / s
    const float n1 = (float)dep;
    const float n2 = (float)(254 - dep);
    const float E1 = __expf(-s2 * n1 * n1);
    const float E2 = __expf(-s2 * n2 * n2);
    const float F1 = c0 * erff(s * n1) + 0.5f * (1.f + E1) - s2 * n1 * E1 * (1.f / 6.f);
    const float F2 = c0 * erff(s * n2) + 0.5f * (1.f + E2) - s2 * n2 * E2 * (1.f / 6.f);
    const float ss = F1 + F2;

    const int W = *feat_w;
    const int2 uv = pts_pos[p];
    const int lin = uv.y * W + uv.x;
    const int slot = atomicAdd(&counts[lin], 1);
    if (slot < CAP) {
        const float A2 = a * LOG2E;
        float4 rec;
        rec.x = __int_as_float(dep);
        rec.y = A2;
        rec.z = rsqrtf(ss);
        rec.w = exp2f(2.0f * A2);           // geometric ratio-of-ratios Q
        bins[(size_t)lin * CAP + slot] = rec;
    }
}

// ---- Pass 2: gather + write in [D, HW] layout. ----
// Block 256 = 4 waves. lane = pixel within a 64-pixel tile; wave + blockIdx.y
// select a 32-depth slab. Inner loop uses the Gaussian recurrence
// g(t+1) = g(t)*r, r *= Q — no transcendentals; one predicated skip at the
// t=0->1 kink (xt repeats there). acc[32] in registers; coalesced 256 B
// output rows; no LDS, no atomics.
// NOTE (R1 post-mortem): the 64-depth/acc[64] variant regressed (+7 µs) —
// bin re-reads across slabs are L3-resident (~zero HBM cost), while the
// doubled recurrence chain + VGPR pressure cost real time AND doubled the
// accumulated rounding error. 32-depth slabs are the sweet spot.
__global__ __launch_bounds__(256) void gather_kernel(
    const int* __restrict__ counts, const float4* __restrict__ bins,
    float* __restrict__ out, int HW)
{
    const int wave = threadIdx.x >> 6;
    const int lane = threadIdx.x & 63;
    const int pix = blockIdx.x * 64 + lane;
    const int db  = blockIdx.y * 128 + wave * 32;   // first depth of this slab

    float acc[32];
#pragma unroll
    for (int k = 0; k < 32; ++k) acc[k] = 0.f;

    if (pix < HW) {
        int cnt = counts[pix];
        cnt = cnt < CAP ? cnt : CAP;
        const float4* __restrict__ rec = bins + (size_t)pix * CAP;
        for (int j = 0; j < cnt; ++j) {
            const float4 r4 = rec[j];
            const int dep   = __float_as_int(r4.x);
            const float A2  = r4.y;
            const float inv = r4.z;
            const float Q   = r4.w;

            const int t0  = db - dep;
            const int xt0 = t0 - (t0 > 0);
            const float fx = (float)xt0;
            float g = exp2f(A2 * fx * fx) * inv;      // inv folded once per rec
            float r = exp2f(A2 * (2.0f * fx + 1.0f));
            const int skipK = -t0;             // at k==skipK, t goes 0->1: xt repeats
#pragma unroll
            for (int k = 0; k < 32; ++k) {
                acc[k] += g;
                const bool adv = (k != skipK);
                g = adv ? g * r : g;
                r = adv ? r * Q : r;
            }
        }
    }

    if (pix < HW) {
#pragma unroll
        for (int k = 0; k < 32; ++k) {
            __builtin_nontemporal_store(acc[k], out + (size_t)(db + k) * HW + pix);
        }
    }
}

// ---------------- Fallback: direct scattered atomics ----------------
__global__ __launch_bounds__(256) void scatter_direct_kernel(
    const int* __restrict__ pts_pos, const int* __restrict__ pts_depth,
    const float* __restrict__ pts_conf, const int* __restrict__ feat_w,
    float* __restrict__ out, int HW, int N)
{
    const int wave = threadIdx.x >> 6;
    const int lane = threadIdx.x & 63;
    const int p = blockIdx.x * 4 + wave;
    if (p >= N) return;

    const int W = *feat_w;
    const int lin = pts_pos[2 * p + 1] * W + pts_pos[2 * p];
    const int dep = pts_depth[p];
    const float ic = 1.0f / pts_conf[p];

    float pr[4];
    float ss = 0.f;
#pragma unroll
    for (int k = 0; k < 4; ++k) {
        const int d = lane + 64 * k;
        const int t = d - dep;
        const float x = (float)(t > 0 ? t - 1 : t) * STEP;
        const float z = x * ic;
        const float e = __expf(-0.5f * z * z);
        pr[k] = e;
        ss += e * e;
    }
#pragma unroll
    for (int off = 32; off; off >>= 1) ss += __shfl_xor(ss, off, 64);
    const float inv = rsqrtf(ss);
#pragma unroll
    for (int k = 0; k < 4; ++k) {
        const int d = lane + 64 * k;
        atomicAdd(out + (size_t)d * HW + lin, pr[k] * inv);
    }
}

extern "C" void kernel_launch(void* const* d_in, const int* in_sizes, int n_in,
                              void* d_out, int out_size, void* d_ws, size_t ws_size,
                              hipStream_t stream) {
    const int*   pts_pos   = (const int*)d_in[0];
    const int*   pts_depth = (const int*)d_in[1];
    const float* pts_conf  = (const float*)d_in[2];
    const int*   feat_w    = (const int*)d_in[4];

    const int N  = in_sizes[0] / 2;
    const int HW = out_size / D_DIM;
    float* out = (float*)d_out;

    // ws layout: [bins: HW*CAP float4 | counts: HW int]
    float4* bins  = (float4*)d_ws;
    int* counts   = (int*)(bins + (size_t)HW * CAP);
    const size_t ws_need = (size_t)HW * CAP * sizeof(float4) + (size_t)HW * sizeof(int);

    if (ws_size >= ws_need) {
        (void)hipMemsetAsync(counts, 0, (size_t)HW * sizeof(int), stream);
        normfill_kernel<<<(N + 255) / 256, 256, 0, stream>>>(
            (const int2*)pts_pos, pts_depth, pts_conf, feat_w, counts, bins, N);
        dim3 grid((HW + 63) / 64, 2);
        gather_kernel<<<grid, 256, 0, stream>>>(counts, bins, out, HW);
    } else {
        (void)hipMemsetAsync(d_out, 0, (size_t)out_size * sizeof(float), stream);
        scatter_direct_kernel<<<(N + 3) / 4, 256, 0, stream>>>(
            pts_pos, pts_depth, pts_conf, feat_w, out, HW, N);
    }
}